// Round 5
// baseline (1060.485 us; speedup 1.0000x reference)
//
#include <hip/hip_runtime.h>
#include <hip/hip_bf16.h>
#include <cmath>

// ---- problem constants ----
#define CC 256
#define WSZ 7
#define WWD_ 56
#define NHD 8
#define HDIM 32
#define KCHN 16
#define KSP 28
#define NTOK 49
#define NWIN 2048
#define NBH 16384
#define LL 3136
#define MTOK 100352
#define MLPH 1024
#define SCALE_Q 0.17677669529663689f

typedef float floatx4 __attribute__((ext_vector_type(4)));
typedef __bf16 bf16x8_t __attribute__((ext_vector_type(8)));

__device__ __forceinline__ float gelu_f(float x) {
    return 0.5f * x * (1.0f + erff(x * 0.7071067811865475f));
}

// async global->LDS DMA, 16B per lane; LDS dest must be wave-uniform base,
// HW writes base + lane*16 (guide §5 / m97 / m151).
__device__ __forceinline__ void lds_dma16(const void* g, void* l) {
    __builtin_amdgcn_global_load_lds((__attribute__((address_space(1))) void*)(void*)g,
                                     (__attribute__((address_space(3))) void*)l, 16, 0, 0);
}

// ---------------- LN1 applied once, rows written in WINDOW ORDER -------------
// Replaces ln_stats_k + per-tile LN staging in gemm_q_k. Bitwise-same formula
// as the old fused staging -> q unchanged.
__global__ __launch_bounds__(64) void xn_k(const float* __restrict__ x,
                                           const float* __restrict__ g,
                                           const float* __restrict__ be,
                                           float* __restrict__ xn) {
    int r = blockIdx.x;          // window-ordered row
    int lane = threadIdx.x;
    int bwi = r / NTOK, n = r - bwi * NTOK;
    int b = bwi >> 6, rem = bwi & 63;
    int hw = rem >> 3, ww = rem & 7;
    int i0 = n / WSZ, j0 = n - i0 * WSZ;
    size_t grow = (size_t)b * LL + (size_t)(hw * WSZ + i0) * WWD_ + (ww * WSZ + j0);
    float4 v = reinterpret_cast<const float4*>(x + grow * CC)[lane];
    float s = v.x + v.y + v.z + v.w;
    float s2 = v.x * v.x + v.y * v.y + v.z * v.z + v.w * v.w;
#pragma unroll
    for (int off = 1; off < 64; off <<= 1) {
        s += __shfl_xor(s, off);
        s2 += __shfl_xor(s2, off);
    }
    float m = s * (1.0f / CC);
    float rsg = rsqrtf(s2 * (1.0f / CC) - m * m + 1e-5f);
    float4 gv = reinterpret_cast<const float4*>(g)[lane];
    float4 bv = reinterpret_cast<const float4*>(be)[lane];
    float4 o = {(v.x - m) * rsg * gv.x + bv.x, (v.y - m) * rsg * gv.y + bv.y,
                (v.z - m) * rsg * gv.z + bv.z, (v.w - m) * rsg * gv.w + bv.w};
    reinterpret_cast<float4*>(xn + (size_t)r * CC)[lane] = o;
}

// ---------------- fp32 GEMM for the q path only (top-k selection needs fp32 q) --------
// BM=64, BN=128, BK=16, 8x4 micro-tile, single-buffered, occupancy-first.
// v3: A comes pre-normalized from xn (window-ordered) -> staging is a bare
// float4 copy; inner loop VALU is nearly pure FMA.
struct GP {
    const float* W;
    const float* bias;
    float* C;
    const float* xn;
};

__global__ __launch_bounds__(256, 6) void gemm_q_k(GP p) {
    __shared__ __align__(16) float As[16][68];    // pad 68: staging writes ~2-way banks
    __shared__ __align__(16) float Bs[16][128];   // linear (DMA), no pad
    const int bm = blockIdx.x * 64;
    const int bn = blockIdx.y * 128;
    const int t = threadIdx.x;
    const int tx = t & 31;   // 32 col-threads * 4 cols = 128
    const int ty = t >> 5;   // 8 row-threads * 8 rows = 64
    const int w = t >> 6;    // wave id

    // A staging indices: 4 threads per row, 4 consecutive k each
    const int ar = t >> 2;          // row 0..63
    const int ak = (t & 3) * 4;     // k offset 0/4/8/12
    const float* arow = p.xn + (size_t)(bm + ar) * CC + ak;

    float acc[8][4] = {};

    for (int k0 = 0; k0 < CC; k0 += 16) {
        {   // stage A: plain copy, transposed to [k][m]
            float4 xv = *reinterpret_cast<const float4*>(arow + k0);
            As[ak + 0][ar] = xv.x;
            As[ak + 1][ar] = xv.y;
            As[ak + 2][ar] = xv.z;
            As[ak + 3][ar] = xv.w;
        }
        // stage B via LDS-DMA: tile 16x128 f32 = 8KB = 512 chunks of 16B.
#pragma unroll
        for (int j = 0; j < 2; ++j) {
            const int c = j * 256 + t;
            const float* gp = p.W + (size_t)((c >> 5) + k0) * CC + bn + (c & 31) * 4;
            lds_dma16(gp, (char*)&Bs[0][0] + j * 4096 + w * 1024);
        }
        __syncthreads();
#pragma unroll
        for (int kk = 0; kk < 16; ++kk) {
            float a[8], bb[4];
            *(float4*)&a[0] = *(const float4*)&As[kk][ty * 8];
            *(float4*)&a[4] = *(const float4*)&As[kk][ty * 8 + 4];
            *(float4*)&bb[0] = *(const float4*)&Bs[kk][tx * 4];
#pragma unroll
            for (int i = 0; i < 8; ++i)
#pragma unroll
                for (int j = 0; j < 4; ++j) acc[i][j] = fmaf(a[i], bb[j], acc[i][j]);
        }
        __syncthreads();
    }

    float bj[4];
#pragma unroll
    for (int j = 0; j < 4; ++j) bj[j] = p.bias[bn + tx * 4 + j];
#pragma unroll
    for (int i = 0; i < 8; ++i) {
        const int row = bm + ty * 8 + i;
        float4 o = {acc[i][0] + bj[0], acc[i][1] + bj[1], acc[i][2] + bj[2], acc[i][3] + bj[3]};
        *reinterpret_cast<float4*>(p.C + (size_t)row * CC + bn + tx * 4) = o;
    }
}

// ---------------- bf16 MFMA GEMM: A (M x K bf16), B (N x K bf16, pre-transposed) -------
// T3-minimum 2-phase: double-buffered LDS; STAGE(t+1) issued BEFORE ds_read/MFMA of
// tile t; single barrier per K-step.
// 1D grid, COLUMN-INNER decode (bn = bid % gy): consecutive blocks share the same
// A-panel -> fetched once from HBM, L2-served for the other gy-1 column blocks.
// EPI: 0 = +bias -> bf16 | 1 = +bias, window-reverse, +resid -> f32
//      2 = +bias, gelu -> bf16 | 3 = +bias, +resid in-place -> f32 (rows offset row0)
struct MG {
    const __hip_bfloat16* A;
    const __hip_bfloat16* B;
    const float* bias;
    int N, K;
    float* Cf;
    __hip_bfloat16* Cb;
    const float* resid;
    int row0;
    int gy;          // column blocks (N/128)
};

template <int EPI>
__global__ __launch_bounds__(256) void mgemm_k(MG p) {
    __shared__ __align__(16) __hip_bfloat16 As[2][128 * 32];
    __shared__ __align__(16) __hip_bfloat16 Bs[2][128 * 32];
    const int bid = blockIdx.x;
    const int bm = (bid / p.gy) * 128;
    const int bn = (bid % p.gy) * 128;
    const int t = threadIdx.x;
    const int lane = t & 63;
    const int w = t >> 6;
    const int wm = (w & 1) * 64;
    const int wn = (w >> 1) * 64;
    const int fr = lane & 15;
    const int fk = (lane >> 4) * 8;

    const int m0 = t >> 2, m1 = (t + 256) >> 2;
    const int kc = (t & 3) * 8;
    const __hip_bfloat16* a0 = p.A + (size_t)(bm + m0) * p.K + kc;
    const __hip_bfloat16* a1 = p.A + (size_t)(bm + m1) * p.K + kc;
    const __hip_bfloat16* b0 = p.B + (size_t)(bn + m0) * p.K + kc;
    const __hip_bfloat16* b1 = p.B + (size_t)(bn + m1) * p.K + kc;

    auto stage = [&](int buf, int k0) {
        lds_dma16(a0 + k0, &As[buf][w * 512]);
        lds_dma16(a1 + k0, &As[buf][2048 + w * 512]);
        lds_dma16(b0 + k0, &Bs[buf][w * 512]);
        lds_dma16(b1 + k0, &Bs[buf][2048 + w * 512]);
    };

    floatx4 acc[4][4] = {};

    stage(0, 0);
    __syncthreads();
    int cur = 0;
    for (int k0 = 0; k0 < p.K; k0 += 32) {
        if (k0 + 32 < p.K) stage(cur ^ 1, k0 + 32);   // prefetch before compute
        bf16x8_t af[4], bf[4];
#pragma unroll
        for (int i = 0; i < 4; ++i)
            af[i] = *(const bf16x8_t*)&As[cur][(wm + i * 16 + fr) * 32 + fk];
#pragma unroll
        for (int j = 0; j < 4; ++j)
            bf[j] = *(const bf16x8_t*)&Bs[cur][(wn + j * 16 + fr) * 32 + fk];
#pragma unroll
        for (int i = 0; i < 4; ++i)
#pragma unroll
            for (int j = 0; j < 4; ++j)
                acc[i][j] = __builtin_amdgcn_mfma_f32_16x16x32_bf16(af[i], bf[j], acc[i][j], 0, 0, 0);
        __syncthreads();   // drains prefetch vmcnt AFTER compute (hidden)
        cur ^= 1;
    }

    // epilogue: C/D layout col = lane&15, row = (lane>>4)*4 + reg  [m89-verified]
    float bj[4];
#pragma unroll
    for (int j = 0; j < 4; ++j) bj[j] = p.bias[bn + wn + j * 16 + fr];
#pragma unroll
    for (int i = 0; i < 4; ++i) {
#pragma unroll
        for (int r = 0; r < 4; ++r) {
            const int m = bm + wm + i * 16 + (lane >> 4) * 4 + r;
#pragma unroll
            for (int j = 0; j < 4; ++j) {
                const int n = bn + wn + j * 16 + fr;
                float v = acc[i][j][r] + bj[j];
                if constexpr (EPI == 0) {
                    p.Cb[(size_t)m * p.N + n] = __float2bfloat16(v);
                } else if constexpr (EPI == 1) {
                    int bwi = m / NTOK, nn = m - bwi * NTOK;
                    int b = bwi >> 6, rem = bwi & 63;
                    int hw = rem >> 3, wwp = rem & 7;
                    int ii = nn / WSZ, jj = nn - ii * WSZ;
                    size_t oidx = ((size_t)b * LL + (size_t)(hw * WSZ + ii) * WWD_ + (wwp * WSZ + jj)) * CC + n;
                    p.Cf[oidx] = v + p.resid[oidx];
                } else if constexpr (EPI == 2) {
                    p.Cb[(size_t)m * p.N + n] = __float2bfloat16(gelu_f(v));
                } else {
                    size_t gr = (size_t)(m + p.row0);
                    p.Cf[gr * p.N + n] = v + p.resid[gr * p.N + n];
                }
            }
        }
    }
}

// ---------------- weight transpose + bf16 convert: W (K x N f32) -> Wt (N x K bf16) ----
__global__ __launch_bounds__(256) void wt_k(const float* __restrict__ W,
                                            __hip_bfloat16* __restrict__ Wt, int K, int N) {
    int g = blockIdx.x * 256 + threadIdx.x;
    if (g >= K * N) return;
    int n = g / K, kk = g - n * K;
    Wt[g] = __float2bfloat16(W[(size_t)kk * N + n]);
}

// ---------------- top-k (channel 16/32, spatial 28/49) ----------------
__global__ __launch_bounds__(64) void topk_k(const float* __restrict__ q,
                                             const float* __restrict__ wch,
                                             const float* __restrict__ bch,
                                             short* __restrict__ cidx,
                                             short* __restrict__ sidx) {
    int bnh = blockIdx.x;
    int bwi = bnh >> 3, h = bnh & 7;
    int lane = threadIdx.x;
    __shared__ float tile[NTOK][HDIM + 1];
    __shared__ float feat[2 * HDIM];
    __shared__ float score[HDIM];
    __shared__ float rowm[NTOK];
    const float* qbase = q + ((size_t)bwi * NTOK) * CC + h * HDIM;
    for (int idx = lane; idx < NTOK * HDIM; idx += 64) {
        int n = idx >> 5, d = idx & 31;
        tile[n][d] = qbase[(size_t)n * CC + d];
    }
    __syncthreads();
    if (lane < HDIM) {
        float s = 0.f, mx = -INFINITY;
        for (int n = 0; n < NTOK; ++n) {
            float v = tile[n][lane];
            s += v;
            mx = fmaxf(mx, v);
        }
        feat[lane] = s * (1.0f / NTOK);
        feat[HDIM + lane] = mx;
    }
    if (lane < NTOK) {
        float s = 0.f;
        for (int d = 0; d < HDIM; ++d) s += tile[lane][d];
        rowm[lane] = s;
    }
    __syncthreads();
    if (lane < HDIM) {
        float s = bch[lane];
        for (int j = 0; j < 2 * HDIM; ++j) s += feat[j] * wch[j * HDIM + lane];
        score[lane] = gelu_f(s);   // softmax is monotonic: skip for top-k
    }
    __syncthreads();
    {
        bool sel = false;
        if (lane < HDIM) {
            float sv = score[lane];
            int rank = 0;
            for (int j = 0; j < HDIM; ++j) {
                float oj = score[j];
                rank += (oj > sv) || (oj == sv && j < lane);
            }
            sel = rank < KCHN;
        }
        unsigned long long m = __ballot(sel);
        if (sel) {
            int pos = __popcll(m & ((1ull << lane) - 1ull));
            cidx[(size_t)bnh * KCHN + pos] = (short)lane;
        }
    }
    {
        bool sel = false;
        if (lane < NTOK) {
            float sv = rowm[lane];
            int rank = 0;
            for (int j = 0; j < NTOK; ++j) {
                float oj = rowm[j];
                rank += (oj > sv) || (oj == sv && j < lane);
            }
            sel = rank < KSP;
        }
        unsigned long long m = __ballot(sel);
        if (sel) {
            int pos = __popcll(m & ((1ull << lane) - 1ull));
            sidx[(size_t)bnh * KSP + pos] = (short)lane;
        }
    }
}

// ---------------- gathers -> bf16 GEMM inputs ----------------
__global__ __launch_bounds__(256) void gather_ch_k(const float* __restrict__ q,
                                                   const short* __restrict__ cidx,
                                                   __hip_bfloat16* __restrict__ ak) {
    int g = blockIdx.x * 256 + threadIdx.x;   // MTOK*128 elements
    int r = g >> 7, kk = g & 127;
    int bwi = r / NTOK;
    int hp = kk >> 4, c = kk & 15;
    int ci = cidx[((size_t)(bwi * NHD + hp)) * KCHN + c];
    ak[g] = __float2bfloat16(q[(size_t)r * CC + hp * HDIM + ci]);
}

__global__ __launch_bounds__(256) void gather_sp_k(const float* __restrict__ q,
                                                   const short* __restrict__ sidx,
                                                   __hip_bfloat16* __restrict__ av) {
    int g = blockIdx.x * 256 + threadIdx.x;   // NWIN*KSP*256 elements
    int rr = g >> 8, c = g & 255;
    int bwi = rr / KSP, s = rr - bwi * KSP;
    int tok = sidx[((size_t)(bwi * NHD + (c >> 5))) * KSP + s];
    av[g] = __float2bfloat16(q[((size_t)(bwi * NTOK + tok)) * CC + c]);
}

// ---------------- attention: one block per WINDOW, 512 thr = 8 waves, wave h = head h --
__global__ __launch_bounds__(512) void attn_k(const float* __restrict__ q,
                                              const __hip_bfloat16* __restrict__ kb,
                                              const __hip_bfloat16* __restrict__ vb,
                                              const short* __restrict__ cidx,
                                              const short* __restrict__ sidx,
                                              const float* __restrict__ rpb,
                                              __hip_bfloat16* __restrict__ ob) {
    const int bwi = blockIdx.x;
    const int tid = threadIdx.x;
    const int h = tid >> 6;
    const int lane = tid & 63;
    __shared__ __hip_bfloat16 kh_s[NTOK][132];   // 12.9 KB, pad 132: reads ~2-way banks
    __shared__ float v_s[KSP][256];              // 28.7 KB
    __shared__ float qs_s[NHD][KSP][KCHN];       // 14.3 KB
    __shared__ int sidx_s[NHD][KSP];
    __shared__ int cidx_s[NHD][KCHN];

    if (tid < NHD * KSP) {
        sidx_s[tid / KSP][tid % KSP] = sidx[(size_t)bwi * NHD * KSP + tid];
    } else if (tid < NHD * KSP + NHD * KCHN) {
        int u = tid - NHD * KSP;
        cidx_s[u / KCHN][u % KCHN] = cidx[(size_t)bwi * NHD * KCHN + u];
    }
    {
        const __hip_bfloat16* kbase = kb + (size_t)bwi * NTOK * (NHD * KCHN);
        for (int ch = tid; ch < NTOK * 16; ch += 512) {
            int n = ch >> 4, c8 = (ch & 15) * 8;
            uint4 u = *(const uint4*)(kbase + n * 128 + c8);
            uint2* dst = (uint2*)&kh_s[n][c8];
            dst[0] = make_uint2(u.x, u.y);
            dst[1] = make_uint2(u.z, u.w);
        }
    }
    {
        const __hip_bfloat16* vbase = vb + (size_t)bwi * KSP * CC;
        for (int ch = tid; ch < KSP * 32; ch += 512) {
            int n = ch >> 5, c8 = (ch & 31) * 8;
            union { uint4 u; __hip_bfloat16 b[8]; } tt;
            tt.u = *(const uint4*)(vbase + n * CC + c8);
#pragma unroll
            for (int j = 0; j < 8; ++j) v_s[n][c8 + j] = __bfloat162float(tt.b[j]);
        }
    }
    __syncthreads();
#pragma unroll
    for (int k = 0; k < 7; ++k) {
        int idx = tid + k * 512;
        int hh = idx / (KSP * KCHN), r = idx - hh * (KSP * KCHN);
        int s = r >> 4, c = r & 15;
        qs_s[hh][s][c] =
            q[((size_t)bwi * NTOK + sidx_s[hh][s]) * CC + hh * HDIM + cidx_s[hh][c]] * SCALE_Q;
    }
    __syncthreads();

    if (lane < NTOK) {
        float khr[16];
        {
            const uint* kp = (const uint*)&kh_s[lane][h * KCHN];
#pragma unroll
            for (int j = 0; j < 8; ++j) {
                uint u = kp[j];
                __hip_bfloat162 b2 = *(__hip_bfloat162*)&u;
                float2 f = __bfloat1622float2(b2);
                khr[2 * j] = f.x;
                khr[2 * j + 1] = f.y;
            }
        }
        int i1 = lane / WSZ, j1 = lane - i1 * WSZ;
        float a[KSP];
        float msum = 0.f;
#pragma unroll
        for (int s = 0; s < KSP; ++s) {
            const float* qrow = &qs_s[h][s][0];
            float dot = 0.f;
#pragma unroll
            for (int c = 0; c < KCHN; ++c) dot += khr[c] * qrow[c];
            int m = sidx_s[h][s];
            int i2 = m / WSZ, j2 = m - i2 * WSZ;
            float bias = rpb[(size_t)((i1 - i2 + 6) * 13 + (j1 - j2 + 6)) * NHD + h];
            a[s] = dot + bias;
            msum += a[s];
        }
        float gate = 1.0f / (1.0f + expf(-msum * (1.0f / KSP)));
        float mx = -INFINITY;
#pragma unroll
        for (int s = 0; s < KSP; ++s) mx = fmaxf(mx, a[s]);
        float sum = 0.f;
#pragma unroll
        for (int s = 0; s < KSP; ++s) {
            a[s] = expf(a[s] - mx);
            sum += a[s];
        }
        float inv = gate / sum;
        float4 ov[8];
#pragma unroll
        for (int d4 = 0; d4 < 8; ++d4) ov[d4] = float4{0.f, 0.f, 0.f, 0.f};
#pragma unroll
        for (int s = 0; s < KSP; ++s) {
            const float4* vrow = (const float4*)&v_s[s][h * HDIM];
            float as = a[s];
#pragma unroll
            for (int d4 = 0; d4 < 8; ++d4) {
                float4 vv = vrow[d4];
                ov[d4].x += as * vv.x;
                ov[d4].y += as * vv.y;
                ov[d4].z += as * vv.z;
                ov[d4].w += as * vv.w;
            }
        }
        __hip_bfloat16* orow = ob + ((size_t)bwi * NTOK + lane) * CC + h * HDIM;
#pragma unroll
        for (int d4 = 0; d4 < 8; ++d4) {
            union { __hip_bfloat16 b[4]; uint2 u; } pk;
            pk.b[0] = __float2bfloat16(ov[d4].x * inv);
            pk.b[1] = __float2bfloat16(ov[d4].y * inv);
            pk.b[2] = __float2bfloat16(ov[d4].z * inv);
            pk.b[3] = __float2bfloat16(ov[d4].w * inv);
            *(uint2*)(orow + d4 * 4) = pk.u;
        }
    }
}

// ---------------- LN2 fused normalize -> bf16 ----------------
__global__ __launch_bounds__(64) void ln2_k(const float* __restrict__ x2,
                                            const float* __restrict__ g,
                                            const float* __restrict__ b,
                                            __hip_bfloat16* __restrict__ a2) {
    int row = blockIdx.x;
    int lane = threadIdx.x;
    float4 v = reinterpret_cast<const float4*>(x2 + (size_t)row * CC)[lane];
    float s = v.x + v.y + v.z + v.w;
    float s2 = v.x * v.x + v.y * v.y + v.z * v.z + v.w * v.w;
#pragma unroll
    for (int off = 1; off < 64; off <<= 1) {
        s += __shfl_xor(s, off);
        s2 += __shfl_xor(s2, off);
    }
    float m = s * (1.0f / CC);
    float rsg = rsqrtf(s2 * (1.0f / CC) - m * m + 1e-5f);
    float4 gv = reinterpret_cast<const float4*>(g)[lane];
    float4 bv = reinterpret_cast<const float4*>(b)[lane];
    __hip_bfloat16* orow = a2 + (size_t)row * CC + lane * 4;
    orow[0] = __float2bfloat16((v.x - m) * rsg * gv.x + bv.x);
    orow[1] = __float2bfloat16((v.y - m) * rsg * gv.y + bv.y);
    orow[2] = __float2bfloat16((v.z - m) * rsg * gv.z + bv.z);
    orow[3] = __float2bfloat16((v.w - m) * rsg * gv.w + bv.w);
}

// ---------------- driver ----------------
extern "C" void kernel_launch(void* const* d_in, const int* in_sizes, int n_in,
                              void* d_out, int out_size, void* d_ws, size_t ws_size,
                              hipStream_t stream) {
    const float* x   = (const float*)d_in[0];
    const float* n1g = (const float*)d_in[1];
    const float* n1b = (const float*)d_in[2];
    const float* wq  = (const float*)d_in[3];
    const float* bq  = (const float*)d_in[4];
    const float* wk  = (const float*)d_in[5];
    const float* bk  = (const float*)d_in[6];
    const float* wv  = (const float*)d_in[7];
    const float* bv  = (const float*)d_in[8];
    const float* wpj = (const float*)d_in[9];
    const float* bpj = (const float*)d_in[10];
    const float* wch = (const float*)d_in[11];
    const float* bch = (const float*)d_in[12];
    const float* rpb = (const float*)d_in[13];
    const float* n2g = (const float*)d_in[14];
    const float* n2b = (const float*)d_in[15];
    const float* w1  = (const float*)d_in[16];
    const float* b1  = (const float*)d_in[17];
    const float* w2  = (const float*)d_in[18];
    const float* b2  = (const float*)d_in[19];
    float* out = (float*)d_out;

    // ---- workspace layout (216,449,024 B) ----
    char* wsb = (char*)d_ws;
    float* qb            = (float*)wsb;                              // 102,760,448 (f32 q)
    float* xn            = (float*)(wsb + 102760448);                // 102,760,448 (LN1'd x, window order; dead after gemm_q)
    __hip_bfloat16* g1   = (__hip_bfloat16*)(wsb + 102760448);       //  25,690,112 (a_k) — overlays dead xn
    __hip_bfloat16* g2   = (__hip_bfloat16*)(wsb + 128450560);       //  29,360,128 (a_v)
    __hip_bfloat16* ob   = g1;                                       //  51,380,224 (o, overlays g1+g2)
    __hip_bfloat16* kb   = (__hip_bfloat16*)(wsb + 157810688);       //  25,690,112
    __hip_bfloat16* vb   = (__hip_bfloat16*)(wsb + 183500800);       //  29,360,128
    short* cidx          = (short*)(wsb + 213663744);
    short* sidx          = (short*)(wsb + 214188032);
    __hip_bfloat16* wkt  = (__hip_bfloat16*)(wsb + 215105536);
    __hip_bfloat16* wvt  = (__hip_bfloat16*)(wsb + 215138304);
    __hip_bfloat16* wpt  = (__hip_bfloat16*)(wsb + 215269376);
    __hip_bfloat16* w1t  = (__hip_bfloat16*)(wsb + 215400448);
    __hip_bfloat16* w2t  = (__hip_bfloat16*)(wsb + 215924736);
    __hip_bfloat16* a2   = (__hip_bfloat16*)qb;                      // overlays dead qb (51 MB)
    __hip_bfloat16* hb   = (__hip_bfloat16*)(wsb + 102760448);       // overlays dead xn/g1/g2 in MLP phase
    if (ws_size < 216449024ULL) return;

    // weight transposes (independent, cheap)
    wt_k<<<(128 * 128 + 255) / 256, 256, 0, stream>>>(wk, wkt, 128, 128);
    wt_k<<<(256 * 256 + 255) / 256, 256, 0, stream>>>(wv, wvt, 256, 256);
    wt_k<<<(256 * 256 + 255) / 256, 256, 0, stream>>>(wpj, wpt, 256, 256);
    wt_k<<<(256 * 1024 + 255) / 256, 256, 0, stream>>>(w1, w1t, 256, 1024);
    wt_k<<<(1024 * 256 + 255) / 256, 256, 0, stream>>>(w2, w2t, 1024, 256);

    // LN1 once, window-ordered rows
    xn_k<<<MTOK, 64, 0, stream>>>(x, n1g, n1b, xn);

    // q (fp32 — protects top-k index selection)
    GP p{};
    p.W = wq; p.bias = bq; p.C = qb; p.xn = xn;
    gemm_q_k<<<dim3(MTOK / 64, 2), 256, 0, stream>>>(p);

    topk_k<<<NBH, 64, 0, stream>>>(qb, wch, bch, cidx, sidx);

    gather_ch_k<<<MTOK * 128 / 256, 256, 0, stream>>>(qb, cidx, g1);
    MG m{};
    m.A = g1; m.B = wkt; m.bias = bk; m.N = 128; m.K = 128; m.Cb = kb; m.gy = 1;
    mgemm_k<0><<<MTOK / 128, 256, 0, stream>>>(m);

    gather_sp_k<<<NWIN * KSP * 256 / 256, 256, 0, stream>>>(qb, sidx, g2);
    m = MG{};
    m.A = g2; m.B = wvt; m.bias = bv; m.N = CC; m.K = CC; m.Cb = vb; m.gy = 2;
    mgemm_k<0><<<(NWIN * KSP / 128) * 2, 256, 0, stream>>>(m);

    attn_k<<<NWIN, 512, 0, stream>>>(qb, kb, vb, cidx, sidx, rpb, ob);

    // out = window_reverse(o @ wproj + bproj) + x
    m = MG{};
    m.A = ob; m.B = wpt; m.bias = bpj; m.N = CC; m.K = CC; m.Cf = out; m.resid = x; m.gy = 2;
    mgemm_k<1><<<(MTOK / 128) * 2, 256, 0, stream>>>(m);

    ln2_k<<<MTOK, 64, 0, stream>>>(out, n2g, n2b, a2);

    const int CHUNK = MTOK / 2;   // hb region fits half of h (102.7 MB)
    for (int c = 0; c < 2; ++c) {
        int start = c * CHUNK;
        m = MG{};
        m.A = a2 + (size_t)start * CC; m.B = w1t; m.bias = b1;
        m.N = MLPH; m.K = CC; m.Cb = hb; m.gy = MLPH / 128;
        mgemm_k<2><<<(CHUNK / 128) * (MLPH / 128), 256, 0, stream>>>(m);

        m = MG{};
        m.A = hb; m.B = w2t; m.bias = b2; m.N = CC; m.K = MLPH;
        m.Cf = out; m.resid = out; m.row0 = start; m.gy = 2;
        mgemm_k<3><<<(CHUNK / 128) * 2, 256, 0, stream>>>(m);
    }
}

// Round 6
// 1048.442 us; speedup vs baseline: 1.0115x; 1.0115x over previous
//
#include <hip/hip_runtime.h>
#include <hip/hip_bf16.h>
#include <cmath>

// ---- problem constants ----
#define CC 256
#define WSZ 7
#define WWD_ 56
#define NHD 8
#define HDIM 32
#define KCHN 16
#define KSP 28
#define NTOK 49
#define NWIN 2048
#define NBH 16384
#define LL 3136
#define MTOK 100352
#define MLPH 1024
#define SCALE_Q 0.17677669529663689f

typedef float floatx4 __attribute__((ext_vector_type(4)));
typedef __bf16 bf16x8_t __attribute__((ext_vector_type(8)));

__device__ __forceinline__ float gelu_f(float x) {
    return 0.5f * x * (1.0f + erff(x * 0.7071067811865475f));
}

// async global->LDS DMA, 16B per lane; LDS dest must be wave-uniform base,
// HW writes base + lane*16 (guide §5 / m97 / m151).
__device__ __forceinline__ void lds_dma16(const void* g, void* l) {
    __builtin_amdgcn_global_load_lds((__attribute__((address_space(1))) void*)(void*)g,
                                     (__attribute__((address_space(3))) void*)l, 16, 0, 0);
}

// ---------------- LN row stats ----------------
__global__ __launch_bounds__(64) void ln_stats_k(const float* __restrict__ x,
                                                 float* __restrict__ mu,
                                                 float* __restrict__ rs) {
    int row = blockIdx.x;
    int lane = threadIdx.x;
    float4 v = reinterpret_cast<const float4*>(x + (size_t)row * CC)[lane];
    float s = v.x + v.y + v.z + v.w;
    float s2 = v.x * v.x + v.y * v.y + v.z * v.z + v.w * v.w;
#pragma unroll
    for (int off = 32; off > 0; off >>= 1) {
        s += __shfl_down(s, off);
        s2 += __shfl_down(s2, off);
    }
    if (lane == 0) {
        float m = s * (1.0f / CC);
        float var = s2 * (1.0f / CC) - m * m;
        mu[row] = m;
        rs[row] = rsqrtf(var + 1e-5f);
    }
}

// ---------------- fp32 GEMM for the q path only (top-k selection needs fp32 q) --------
// v4: BM=64, BN=256 (=N, x read ONCE), BK=16, 8x8 micro-tile (64 FMA / 4 ds_read_b128
// per kk — 2x the FMA density of the 8x4 round-5 version whose VALU ratio capped it
// at 49% FMA-issue). Single-buffered (round-3 lesson: occupancy over explicit dbuf);
// conflict-free split-column b-reads (round-2); LN fused into A staging (round-4).
struct GP {
    const float* W;
    const float* bias;
    float* C;
    const float* x;
    const float* mu;
    const float* rs;
    const float* g;
    const float* be;
};

__global__ __launch_bounds__(256, 4) void gemm_q_k(GP p) {
    __shared__ __align__(16) float As[16][68];    // pad 68: staging writes ~2-way banks
    __shared__ __align__(16) float Bs[16][256];   // linear (DMA), no pad
    const int bm = blockIdx.x * 64;
    const int t = threadIdx.x;
    const int tx = t & 31;   // 32 col-threads; cols {tx*4..+3, 128+tx*4..+3}
    const int ty = t >> 5;   // 8 row-threads * 8 rows = 64
    const int w = t >> 6;    // wave id

    // A staging indices: 4 threads per row, 4 consecutive k each
    const int ar = t >> 2;          // row 0..63
    const int ak = (t & 3) * 4;     // k offset 0/4/8/12

    // LN1 + window-partition fused into A load (round-4-verified)
    const int r = bm + ar;
    int bwi = r / NTOK, n = r - bwi * NTOK;
    int b = bwi >> 6, rem = bwi & 63;
    int hw = rem >> 3, ww = rem & 7;
    int i0 = n / WSZ, j0 = n - i0 * WSZ;
    size_t grow = (size_t)b * LL + (size_t)(hw * WSZ + i0) * WWD_ + (ww * WSZ + j0);
    const float m = p.mu[grow], rsg = p.rs[grow];
    const float* xrow = p.x + grow * CC + ak;
    const float* gl = p.g + ak;
    const float* bl = p.be + ak;

    float acc[8][8] = {};

    for (int k0 = 0; k0 < CC; k0 += 16) {
        {   // stage A (LN fused), transposed to [k][m]
            float4 xv = *reinterpret_cast<const float4*>(xrow + k0);
            float4 gv = *reinterpret_cast<const float4*>(gl + k0);
            float4 bv = *reinterpret_cast<const float4*>(bl + k0);
            As[ak + 0][ar] = (xv.x - m) * rsg * gv.x + bv.x;
            As[ak + 1][ar] = (xv.y - m) * rsg * gv.y + bv.y;
            As[ak + 2][ar] = (xv.z - m) * rsg * gv.z + bv.z;
            As[ak + 3][ar] = (xv.w - m) * rsg * gv.w + bv.w;
        }
        // stage B via LDS-DMA: tile 16x256 f32 = 16KB = 1024 chunks of 16B.
        // chunk c -> row c>>6, float4 c&63; LDS byte = c*16 (linear in t);
        // each wave's 64 lanes cover exactly one 1KB global row -> coalesced.
#pragma unroll
        for (int j = 0; j < 4; ++j) {
            const int c = j * 256 + t;
            const float* gp = p.W + (size_t)(k0 + (c >> 6)) * CC + (c & 63) * 4;
            lds_dma16(gp, (char*)&Bs[0][0] + j * 4096 + w * 1024);
        }
        __syncthreads();
#pragma unroll
        for (int kk = 0; kk < 16; ++kk) {
            float a[8], bb[8];
            *(float4*)&a[0] = *(const float4*)&As[kk][ty * 8];
            *(float4*)&a[4] = *(const float4*)&As[kk][ty * 8 + 4];
            *(float4*)&bb[0] = *(const float4*)&Bs[kk][tx * 4];         // lanes: 512B contig
            *(float4*)&bb[4] = *(const float4*)&Bs[kk][128 + tx * 4];   // conflict-free
#pragma unroll
            for (int i = 0; i < 8; ++i)
#pragma unroll
                for (int j = 0; j < 8; ++j) acc[i][j] = fmaf(a[i], bb[j], acc[i][j]);
        }
        __syncthreads();
    }

    // epilogue: cols j<4 -> tx*4+j ; j>=4 -> 128+tx*4+(j-4)
    float bj0[4], bj1[4];
#pragma unroll
    for (int j = 0; j < 4; ++j) {
        bj0[j] = p.bias[tx * 4 + j];
        bj1[j] = p.bias[128 + tx * 4 + j];
    }
#pragma unroll
    for (int i = 0; i < 8; ++i) {
        const int row = bm + ty * 8 + i;
        float* crow = p.C + (size_t)row * CC;
        float4 o0 = {acc[i][0] + bj0[0], acc[i][1] + bj0[1], acc[i][2] + bj0[2], acc[i][3] + bj0[3]};
        float4 o1 = {acc[i][4] + bj1[0], acc[i][5] + bj1[1], acc[i][6] + bj1[2], acc[i][7] + bj1[3]};
        *reinterpret_cast<float4*>(crow + tx * 4) = o0;
        *reinterpret_cast<float4*>(crow + 128 + tx * 4) = o1;
    }
}

// ---------------- bf16 MFMA GEMM: A (M x K bf16), B (N x K bf16, pre-transposed) -------
// T3-minimum 2-phase: double-buffered LDS; STAGE(t+1) issued BEFORE ds_read/MFMA of
// tile t; single barrier per K-step.
// 1D grid, COLUMN-INNER decode (bn = bid % gy): consecutive blocks share the same
// A-panel -> fetched once from HBM, L2-served for the other gy-1 column blocks.
// EPI: 0 = +bias -> bf16 | 1 = +bias, window-reverse, +resid -> f32
//      2 = +bias, gelu -> bf16 | 3 = +bias, +resid in-place -> f32 (rows offset row0)
struct MG {
    const __hip_bfloat16* A;
    const __hip_bfloat16* B;
    const float* bias;
    int N, K;
    float* Cf;
    __hip_bfloat16* Cb;
    const float* resid;
    int row0;
    int gy;          // column blocks (N/128)
};

template <int EPI>
__global__ __launch_bounds__(256) void mgemm_k(MG p) {
    __shared__ __align__(16) __hip_bfloat16 As[2][128 * 32];
    __shared__ __align__(16) __hip_bfloat16 Bs[2][128 * 32];
    const int bid = blockIdx.x;
    const int bm = (bid / p.gy) * 128;
    const int bn = (bid % p.gy) * 128;
    const int t = threadIdx.x;
    const int lane = t & 63;
    const int w = t >> 6;
    const int wm = (w & 1) * 64;
    const int wn = (w >> 1) * 64;
    const int fr = lane & 15;
    const int fk = (lane >> 4) * 8;

    const int m0 = t >> 2, m1 = (t + 256) >> 2;
    const int kc = (t & 3) * 8;
    const __hip_bfloat16* a0 = p.A + (size_t)(bm + m0) * p.K + kc;
    const __hip_bfloat16* a1 = p.A + (size_t)(bm + m1) * p.K + kc;
    const __hip_bfloat16* b0 = p.B + (size_t)(bn + m0) * p.K + kc;
    const __hip_bfloat16* b1 = p.B + (size_t)(bn + m1) * p.K + kc;

    auto stage = [&](int buf, int k0) {
        lds_dma16(a0 + k0, &As[buf][w * 512]);
        lds_dma16(a1 + k0, &As[buf][2048 + w * 512]);
        lds_dma16(b0 + k0, &Bs[buf][w * 512]);
        lds_dma16(b1 + k0, &Bs[buf][2048 + w * 512]);
    };

    floatx4 acc[4][4] = {};

    stage(0, 0);
    __syncthreads();
    int cur = 0;
    for (int k0 = 0; k0 < p.K; k0 += 32) {
        if (k0 + 32 < p.K) stage(cur ^ 1, k0 + 32);   // prefetch before compute
        bf16x8_t af[4], bf[4];
#pragma unroll
        for (int i = 0; i < 4; ++i)
            af[i] = *(const bf16x8_t*)&As[cur][(wm + i * 16 + fr) * 32 + fk];
#pragma unroll
        for (int j = 0; j < 4; ++j)
            bf[j] = *(const bf16x8_t*)&Bs[cur][(wn + j * 16 + fr) * 32 + fk];
#pragma unroll
        for (int i = 0; i < 4; ++i)
#pragma unroll
            for (int j = 0; j < 4; ++j)
                acc[i][j] = __builtin_amdgcn_mfma_f32_16x16x32_bf16(af[i], bf[j], acc[i][j], 0, 0, 0);
        __syncthreads();   // drains prefetch vmcnt AFTER compute (hidden)
        cur ^= 1;
    }

    // epilogue: C/D layout col = lane&15, row = (lane>>4)*4 + reg  [m89-verified]
    float bj[4];
#pragma unroll
    for (int j = 0; j < 4; ++j) bj[j] = p.bias[bn + wn + j * 16 + fr];
#pragma unroll
    for (int i = 0; i < 4; ++i) {
#pragma unroll
        for (int r = 0; r < 4; ++r) {
            const int m = bm + wm + i * 16 + (lane >> 4) * 4 + r;
#pragma unroll
            for (int j = 0; j < 4; ++j) {
                const int n = bn + wn + j * 16 + fr;
                float v = acc[i][j][r] + bj[j];
                if constexpr (EPI == 0) {
                    p.Cb[(size_t)m * p.N + n] = __float2bfloat16(v);
                } else if constexpr (EPI == 1) {
                    int bwi = m / NTOK, nn = m - bwi * NTOK;
                    int b = bwi >> 6, rem = bwi & 63;
                    int hw = rem >> 3, wwp = rem & 7;
                    int ii = nn / WSZ, jj = nn - ii * WSZ;
                    size_t oidx = ((size_t)b * LL + (size_t)(hw * WSZ + ii) * WWD_ + (wwp * WSZ + jj)) * CC + n;
                    p.Cf[oidx] = v + p.resid[oidx];
                } else if constexpr (EPI == 2) {
                    p.Cb[(size_t)m * p.N + n] = __float2bfloat16(gelu_f(v));
                } else {
                    size_t gr = (size_t)(m + p.row0);
                    p.Cf[gr * p.N + n] = v + p.resid[gr * p.N + n];
                }
            }
        }
    }
}

// ---------------- weight transpose + bf16 convert: W (K x N f32) -> Wt (N x K bf16) ----
__global__ __launch_bounds__(256) void wt_k(const float* __restrict__ W,
                                            __hip_bfloat16* __restrict__ Wt, int K, int N) {
    int g = blockIdx.x * 256 + threadIdx.x;
    if (g >= K * N) return;
    int n = g / K, kk = g - n * K;
    Wt[g] = __float2bfloat16(W[(size_t)kk * N + n]);
}

// ---------------- top-k (channel 16/32, spatial 28/49) ----------------
__global__ __launch_bounds__(64) void topk_k(const float* __restrict__ q,
                                             const float* __restrict__ wch,
                                             const float* __restrict__ bch,
                                             short* __restrict__ cidx,
                                             short* __restrict__ sidx) {
    int bnh = blockIdx.x;
    int bwi = bnh >> 3, h = bnh & 7;
    int lane = threadIdx.x;
    __shared__ float tile[NTOK][HDIM + 1];
    __shared__ float feat[2 * HDIM];
    __shared__ float score[HDIM];
    __shared__ float rowm[NTOK];
    const float* qbase = q + ((size_t)bwi * NTOK) * CC + h * HDIM;
    for (int idx = lane; idx < NTOK * HDIM; idx += 64) {
        int n = idx >> 5, d = idx & 31;
        tile[n][d] = qbase[(size_t)n * CC + d];
    }
    __syncthreads();
    if (lane < HDIM) {
        float s = 0.f, mx = -INFINITY;
        for (int n = 0; n < NTOK; ++n) {
            float v = tile[n][lane];
            s += v;
            mx = fmaxf(mx, v);
        }
        feat[lane] = s * (1.0f / NTOK);
        feat[HDIM + lane] = mx;
    }
    if (lane < NTOK) {
        float s = 0.f;
        for (int d = 0; d < HDIM; ++d) s += tile[lane][d];
        rowm[lane] = s;
    }
    __syncthreads();
    if (lane < HDIM) {
        float s = bch[lane];
        for (int j = 0; j < 2 * HDIM; ++j) s += feat[j] * wch[j * HDIM + lane];
        score[lane] = gelu_f(s);   // softmax is monotonic: skip for top-k
    }
    __syncthreads();
    {
        bool sel = false;
        if (lane < HDIM) {
            float sv = score[lane];
            int rank = 0;
            for (int j = 0; j < HDIM; ++j) {
                float oj = score[j];
                rank += (oj > sv) || (oj == sv && j < lane);
            }
            sel = rank < KCHN;
        }
        unsigned long long m = __ballot(sel);
        if (sel) {
            int pos = __popcll(m & ((1ull << lane) - 1ull));
            cidx[(size_t)bnh * KCHN + pos] = (short)lane;
        }
    }
    {
        bool sel = false;
        if (lane < NTOK) {
            float sv = rowm[lane];
            int rank = 0;
            for (int j = 0; j < NTOK; ++j) {
                float oj = rowm[j];
                rank += (oj > sv) || (oj == sv && j < lane);
            }
            sel = rank < KSP;
        }
        unsigned long long m = __ballot(sel);
        if (sel) {
            int pos = __popcll(m & ((1ull << lane) - 1ull));
            sidx[(size_t)bnh * KSP + pos] = (short)lane;
        }
    }
}

// ---------------- gathers -> bf16 GEMM inputs ----------------
__global__ __launch_bounds__(256) void gather_ch_k(const float* __restrict__ q,
                                                   const short* __restrict__ cidx,
                                                   __hip_bfloat16* __restrict__ ak) {
    int g = blockIdx.x * 256 + threadIdx.x;   // MTOK*128 elements
    int r = g >> 7, kk = g & 127;
    int bwi = r / NTOK;
    int hp = kk >> 4, c = kk & 15;
    int ci = cidx[((size_t)(bwi * NHD + hp)) * KCHN + c];
    ak[g] = __float2bfloat16(q[(size_t)r * CC + hp * HDIM + ci]);
}

__global__ __launch_bounds__(256) void gather_sp_k(const float* __restrict__ q,
                                                   const short* __restrict__ sidx,
                                                   __hip_bfloat16* __restrict__ av) {
    int g = blockIdx.x * 256 + threadIdx.x;   // NWIN*KSP*256 elements
    int rr = g >> 8, c = g & 255;
    int bwi = rr / KSP, s = rr - bwi * KSP;
    int tok = sidx[((size_t)(bwi * NHD + (c >> 5))) * KSP + s];
    av[g] = __float2bfloat16(q[((size_t)(bwi * NTOK + tok)) * CC + c]);
}

// ---------------- attention: one block per WINDOW, 512 thr = 8 waves, wave h = head h --
__global__ __launch_bounds__(512) void attn_k(const float* __restrict__ q,
                                              const __hip_bfloat16* __restrict__ kb,
                                              const __hip_bfloat16* __restrict__ vb,
                                              const short* __restrict__ cidx,
                                              const short* __restrict__ sidx,
                                              const float* __restrict__ rpb,
                                              __hip_bfloat16* __restrict__ ob) {
    const int bwi = blockIdx.x;
    const int tid = threadIdx.x;
    const int h = tid >> 6;
    const int lane = tid & 63;
    __shared__ __hip_bfloat16 kh_s[NTOK][132];   // 12.9 KB, pad 132: reads ~2-way banks
    __shared__ float v_s[KSP][256];              // 28.7 KB
    __shared__ float qs_s[NHD][KSP][KCHN];       // 14.3 KB
    __shared__ int sidx_s[NHD][KSP];
    __shared__ int cidx_s[NHD][KCHN];

    if (tid < NHD * KSP) {
        sidx_s[tid / KSP][tid % KSP] = sidx[(size_t)bwi * NHD * KSP + tid];
    } else if (tid < NHD * KSP + NHD * KCHN) {
        int u = tid - NHD * KSP;
        cidx_s[u / KCHN][u % KCHN] = cidx[(size_t)bwi * NHD * KCHN + u];
    }
    {
        const __hip_bfloat16* kbase = kb + (size_t)bwi * NTOK * (NHD * KCHN);
        for (int ch = tid; ch < NTOK * 16; ch += 512) {
            int n = ch >> 4, c8 = (ch & 15) * 8;
            uint4 u = *(const uint4*)(kbase + n * 128 + c8);
            uint2* dst = (uint2*)&kh_s[n][c8];
            dst[0] = make_uint2(u.x, u.y);
            dst[1] = make_uint2(u.z, u.w);
        }
    }
    {
        const __hip_bfloat16* vbase = vb + (size_t)bwi * KSP * CC;
        for (int ch = tid; ch < KSP * 32; ch += 512) {
            int n = ch >> 5, c8 = (ch & 31) * 8;
            union { uint4 u; __hip_bfloat16 b[8]; } tt;
            tt.u = *(const uint4*)(vbase + n * CC + c8);
#pragma unroll
            for (int j = 0; j < 8; ++j) v_s[n][c8 + j] = __bfloat162float(tt.b[j]);
        }
    }
    __syncthreads();
#pragma unroll
    for (int k = 0; k < 7; ++k) {
        int idx = tid + k * 512;
        int hh = idx / (KSP * KCHN), r = idx - hh * (KSP * KCHN);
        int s = r >> 4, c = r & 15;
        qs_s[hh][s][c] =
            q[((size_t)bwi * NTOK + sidx_s[hh][s]) * CC + hh * HDIM + cidx_s[hh][c]] * SCALE_Q;
    }
    __syncthreads();

    if (lane < NTOK) {
        float khr[16];
        {
            const uint* kp = (const uint*)&kh_s[lane][h * KCHN];
#pragma unroll
            for (int j = 0; j < 8; ++j) {
                uint u = kp[j];
                __hip_bfloat162 b2 = *(__hip_bfloat162*)&u;
                float2 f = __bfloat1622float2(b2);
                khr[2 * j] = f.x;
                khr[2 * j + 1] = f.y;
            }
        }
        int i1 = lane / WSZ, j1 = lane - i1 * WSZ;
        float a[KSP];
        float msum = 0.f;
#pragma unroll
        for (int s = 0; s < KSP; ++s) {
            const float* qrow = &qs_s[h][s][0];
            float dot = 0.f;
#pragma unroll
            for (int c = 0; c < KCHN; ++c) dot += khr[c] * qrow[c];
            int m = sidx_s[h][s];
            int i2 = m / WSZ, j2 = m - i2 * WSZ;
            float bias = rpb[(size_t)((i1 - i2 + 6) * 13 + (j1 - j2 + 6)) * NHD + h];
            a[s] = dot + bias;
            msum += a[s];
        }
        float gate = 1.0f / (1.0f + expf(-msum * (1.0f / KSP)));
        float mx = -INFINITY;
#pragma unroll
        for (int s = 0; s < KSP; ++s) mx = fmaxf(mx, a[s]);
        float sum = 0.f;
#pragma unroll
        for (int s = 0; s < KSP; ++s) {
            a[s] = expf(a[s] - mx);
            sum += a[s];
        }
        float inv = gate / sum;
        float4 ov[8];
#pragma unroll
        for (int d4 = 0; d4 < 8; ++d4) ov[d4] = float4{0.f, 0.f, 0.f, 0.f};
#pragma unroll
        for (int s = 0; s < KSP; ++s) {
            const float4* vrow = (const float4*)&v_s[s][h * HDIM];
            float as = a[s];
#pragma unroll
            for (int d4 = 0; d4 < 8; ++d4) {
                float4 vv = vrow[d4];
                ov[d4].x += as * vv.x;
                ov[d4].y += as * vv.y;
                ov[d4].z += as * vv.z;
                ov[d4].w += as * vv.w;
            }
        }
        __hip_bfloat16* orow = ob + ((size_t)bwi * NTOK + lane) * CC + h * HDIM;
#pragma unroll
        for (int d4 = 0; d4 < 8; ++d4) {
            union { __hip_bfloat16 b[4]; uint2 u; } pk;
            pk.b[0] = __float2bfloat16(ov[d4].x * inv);
            pk.b[1] = __float2bfloat16(ov[d4].y * inv);
            pk.b[2] = __float2bfloat16(ov[d4].z * inv);
            pk.b[3] = __float2bfloat16(ov[d4].w * inv);
            *(uint2*)(orow + d4 * 4) = pk.u;
        }
    }
}

// ---------------- LN2 fused normalize -> bf16 ----------------
__global__ __launch_bounds__(64) void ln2_k(const float* __restrict__ x2,
                                            const float* __restrict__ g,
                                            const float* __restrict__ b,
                                            __hip_bfloat16* __restrict__ a2) {
    int row = blockIdx.x;
    int lane = threadIdx.x;
    float4 v = reinterpret_cast<const float4*>(x2 + (size_t)row * CC)[lane];
    float s = v.x + v.y + v.z + v.w;
    float s2 = v.x * v.x + v.y * v.y + v.z * v.z + v.w * v.w;
#pragma unroll
    for (int off = 1; off < 64; off <<= 1) {
        s += __shfl_xor(s, off);
        s2 += __shfl_xor(s2, off);
    }
    float m = s * (1.0f / CC);
    float rsg = rsqrtf(s2 * (1.0f / CC) - m * m + 1e-5f);
    float4 gv = reinterpret_cast<const float4*>(g)[lane];
    float4 bv = reinterpret_cast<const float4*>(b)[lane];
    __hip_bfloat16* orow = a2 + (size_t)row * CC + lane * 4;
    orow[0] = __float2bfloat16((v.x - m) * rsg * gv.x + bv.x);
    orow[1] = __float2bfloat16((v.y - m) * rsg * gv.y + bv.y);
    orow[2] = __float2bfloat16((v.z - m) * rsg * gv.z + bv.z);
    orow[3] = __float2bfloat16((v.w - m) * rsg * gv.w + bv.w);
}

// ---------------- driver ----------------
extern "C" void kernel_launch(void* const* d_in, const int* in_sizes, int n_in,
                              void* d_out, int out_size, void* d_ws, size_t ws_size,
                              hipStream_t stream) {
    const float* x   = (const float*)d_in[0];
    const float* n1g = (const float*)d_in[1];
    const float* n1b = (const float*)d_in[2];
    const float* wq  = (const float*)d_in[3];
    const float* bq  = (const float*)d_in[4];
    const float* wk  = (const float*)d_in[5];
    const float* bk  = (const float*)d_in[6];
    const float* wv  = (const float*)d_in[7];
    const float* bv  = (const float*)d_in[8];
    const float* wpj = (const float*)d_in[9];
    const float* bpj = (const float*)d_in[10];
    const float* wch = (const float*)d_in[11];
    const float* bch = (const float*)d_in[12];
    const float* rpb = (const float*)d_in[13];
    const float* n2g = (const float*)d_in[14];
    const float* n2b = (const float*)d_in[15];
    const float* w1  = (const float*)d_in[16];
    const float* b1  = (const float*)d_in[17];
    const float* w2  = (const float*)d_in[18];
    const float* b2  = (const float*)d_in[19];
    float* out = (float*)d_out;

    // ---- workspace layout (216,449,024 B) ----
    char* wsb = (char*)d_ws;
    float* qb            = (float*)wsb;                              // 102,760,448 (f32 q)
    __hip_bfloat16* g1   = (__hip_bfloat16*)(wsb + 102760448);       //  25,690,112 (a_k)
    __hip_bfloat16* g2   = (__hip_bfloat16*)(wsb + 128450560);       //  29,360,128 (a_v)
    __hip_bfloat16* ob   = g1;                                       //  51,380,224 (o, overlays g1+g2)
    __hip_bfloat16* kb   = (__hip_bfloat16*)(wsb + 157810688);       //  25,690,112
    __hip_bfloat16* vb   = (__hip_bfloat16*)(wsb + 183500800);       //  29,360,128
    float* mu1           = (float*)(wsb + 212860928);
    float* rs1           = mu1 + MTOK;
    short* cidx          = (short*)(wsb + 213663744);
    short* sidx          = (short*)(wsb + 214188032);
    __hip_bfloat16* wkt  = (__hip_bfloat16*)(wsb + 215105536);
    __hip_bfloat16* wvt  = (__hip_bfloat16*)(wsb + 215138304);
    __hip_bfloat16* wpt  = (__hip_bfloat16*)(wsb + 215269376);
    __hip_bfloat16* w1t  = (__hip_bfloat16*)(wsb + 215400448);
    __hip_bfloat16* w2t  = (__hip_bfloat16*)(wsb + 215924736);
    __hip_bfloat16* a2   = (__hip_bfloat16*)qb;                      // overlays dead qb (51 MB)
    __hip_bfloat16* hb   = (__hip_bfloat16*)(wsb + 102760448);       // overlays dead g1/g2 in MLP phase
    if (ws_size < 216449024ULL) return;

    // weight transposes (independent, cheap)
    wt_k<<<(128 * 128 + 255) / 256, 256, 0, stream>>>(wk, wkt, 128, 128);
    wt_k<<<(256 * 256 + 255) / 256, 256, 0, stream>>>(wv, wvt, 256, 256);
    wt_k<<<(256 * 256 + 255) / 256, 256, 0, stream>>>(wpj, wpt, 256, 256);
    wt_k<<<(256 * 1024 + 255) / 256, 256, 0, stream>>>(w1, w1t, 256, 1024);
    wt_k<<<(1024 * 256 + 255) / 256, 256, 0, stream>>>(w2, w2t, 1024, 256);

    ln_stats_k<<<MTOK, 64, 0, stream>>>(x, mu1, rs1);

    // q (fp32 — protects top-k index selection)
    GP p{};
    p.W = wq; p.bias = bq; p.C = qb;
    p.x = x; p.mu = mu1; p.rs = rs1; p.g = n1g; p.be = n1b;
    gemm_q_k<<<dim3(MTOK / 64), 256, 0, stream>>>(p);

    topk_k<<<NBH, 64, 0, stream>>>(qb, wch, bch, cidx, sidx);

    gather_ch_k<<<MTOK * 128 / 256, 256, 0, stream>>>(qb, cidx, g1);
    MG m{};
    m.A = g1; m.B = wkt; m.bias = bk; m.N = 128; m.K = 128; m.Cb = kb; m.gy = 1;
    mgemm_k<0><<<MTOK / 128, 256, 0, stream>>>(m);

    gather_sp_k<<<NWIN * KSP * 256 / 256, 256, 0, stream>>>(qb, sidx, g2);
    m = MG{};
    m.A = g2; m.B = wvt; m.bias = bv; m.N = CC; m.K = CC; m.Cb = vb; m.gy = 2;
    mgemm_k<0><<<(NWIN * KSP / 128) * 2, 256, 0, stream>>>(m);

    attn_k<<<NWIN, 512, 0, stream>>>(qb, kb, vb, cidx, sidx, rpb, ob);

    // out = window_reverse(o @ wproj + bproj) + x
    m = MG{};
    m.A = ob; m.B = wpt; m.bias = bpj; m.N = CC; m.K = CC; m.Cf = out; m.resid = x; m.gy = 2;
    mgemm_k<1><<<(MTOK / 128) * 2, 256, 0, stream>>>(m);

    ln2_k<<<MTOK, 64, 0, stream>>>(out, n2g, n2b, a2);

    const int CHUNK = MTOK / 2;   // hb region fits half of h (102.7 MB)
    for (int c = 0; c < 2; ++c) {
        int start = c * CHUNK;
        m = MG{};
        m.A = a2 + (size_t)start * CC; m.B = w1t; m.bias = b1;
        m.N = MLPH; m.K = CC; m.Cb = hb; m.gy = MLPH / 128;
        mgemm_k<2><<<(CHUNK / 128) * (MLPH / 128), 256, 0, stream>>>(m);

        m = MG{};
        m.A = hb; m.B = w2t; m.bias = b2; m.N = CC; m.K = MLPH;
        m.Cf = out; m.resid = out; m.row0 = start; m.gy = 2;
        mgemm_k<3><<<(CHUNK / 128) * 2, 256, 0, stream>>>(m);
    }
}